// Round 1
// baseline (137.406 us; speedup 1.0000x reference)
//
#include <hip/hip_runtime.h>

// Updater: B=4194304 sequential scan, state = 3 independent scalar recurrences
//   net' = sigmoid(10*(net + u - 0.5)),  u = W*x + b,  pred = x . net'
// Parallelized via chunked scan + certified warm-up:
//   monotone map => bracket [lo,hi] from inits {0,1} bounds the true state.
//   If bracket width < 1e-6 at chunk start -> proceed; else geometric backoff
//   (4x warm-up) until converged or reaching t=0 (exact net0 init).

namespace {
constexpr int BTOT  = 4194304;
constexpr int CHUNK = 32;                 // steps per thread
constexpr int WARM  = 128;                // first-attempt warm-up length
constexpr int BLOCK = 256;
constexpr int NTHR  = BTOT / CHUNK;       // 131072
constexpr int GRID  = NTHR / BLOCK;       // 512
}

__device__ __forceinline__ float sig10(float z) {
    // sigmoid(10*z) = 1 / (1 + exp(-10*z)); v_exp_f32 + v_rcp_f32
    return __builtin_amdgcn_rcpf(1.0f + __expf(-10.0f * z));
}

// warm-up step: advance both bracket trajectories (no pred)
#define US(X0, X1, X2)                                                   \
  do {                                                                   \
    const float u0 = fmaf(w00, (X0), fmaf(w01, (X1), fmaf(w02, (X2), b0))); \
    const float u1 = fmaf(w10, (X0), fmaf(w11, (X1), fmaf(w12, (X2), b1))); \
    const float u2 = fmaf(w20, (X0), fmaf(w21, (X1), fmaf(w22, (X2), b2))); \
    lo0 = sig10(lo0 + u0 - 0.5f);  hi0 = sig10(hi0 + u0 - 0.5f);         \
    lo1 = sig10(lo1 + u1 - 0.5f);  hi1 = sig10(hi1 + u1 - 0.5f);         \
    lo2 = sig10(lo2 + u2 - 0.5f);  hi2 = sig10(hi2 + u2 - 0.5f);         \
  } while (0)

// main step: advance state, record pred
#define MS(IDX, X0, X1, X2)                                              \
  do {                                                                   \
    const float u0 = fmaf(w00, (X0), fmaf(w01, (X1), fmaf(w02, (X2), b0))); \
    const float u1 = fmaf(w10, (X0), fmaf(w11, (X1), fmaf(w12, (X2), b1))); \
    const float u2 = fmaf(w20, (X0), fmaf(w21, (X1), fmaf(w22, (X2), b2))); \
    m0 = sig10(m0 + u0 - 0.5f);                                          \
    m1 = sig10(m1 + u1 - 0.5f);                                          \
    m2 = sig10(m2 + u2 - 0.5f);                                          \
    pr[(IDX)] = fmaf((X0), m0, fmaf((X1), m1, (X2) * m2));               \
  } while (0)

__global__ __launch_bounds__(BLOCK) void Updater_65395172049297_kernel(
    const float* __restrict__ x, const float* __restrict__ W,
    const float* __restrict__ bv, const float* __restrict__ n0v,
    float* __restrict__ out)
{
    const int  tid   = blockIdx.x * BLOCK + threadIdx.x;
    const long start = (long)tid * CHUNK;

    const float w00 = W[0], w01 = W[1], w02 = W[2];
    const float w10 = W[3], w11 = W[4], w12 = W[5];
    const float w20 = W[6], w21 = W[7], w22 = W[8];
    const float b0  = bv[0], b1 = bv[1], b2 = bv[2];
    const float n00 = n0v[0], n01 = n0v[1], n02 = n0v[2];

    float lo0 = 0.f, lo1 = 0.f, lo2 = 0.f;
    float hi0 = 1.f, hi1 = 1.f, hi2 = 1.f;

    bool done = false;
    for (int attempt = 0; attempt < 12 && !done; ++attempt) {
        const long wl    = (long)WARM << (2 * attempt);   // 128, 512, 2048, ...
        long       begin = start - wl;
        bool       exact = false;
        if (begin <= 0) { begin = 0; exact = true; }
        if (exact) {
            lo0 = hi0 = n00; lo1 = hi1 = n01; lo2 = hi2 = n02;
        } else {
            lo0 = lo1 = lo2 = 0.0f; hi0 = hi1 = hi2 = 1.0f;
        }
        // begin is a multiple of 32 -> x+3*begin is 384B aligned -> float4 ok
        const float4* wp = reinterpret_cast<const float4*>(x + 3 * begin);
        const long    ng = (start - begin) >> 2;          // 4 steps / group
        float4 pa, pb, pc;
        if (ng > 0) { pa = wp[0]; pb = wp[1]; pc = wp[2]; }
        for (long g = 0; g < ng; ++g) {
            float4 na, nb, nc;
            const bool more = (g + 1 < ng);
            if (more) { na = wp[3*g+3]; nb = wp[3*g+4]; nc = wp[3*g+5]; }
            US(pa.x, pa.y, pa.z);
            US(pa.w, pb.x, pb.y);
            US(pb.z, pb.w, pc.x);
            US(pc.y, pc.z, pc.w);
            if (more) { pa = na; pb = nb; pc = nc; }
        }
        done = exact || (((hi0 - lo0) < 1e-6f) & ((hi1 - lo1) < 1e-6f) &
                         ((hi2 - lo2) < 1e-6f));
    }

    // ---- main chunk ----
    float m0 = 0.5f * (lo0 + hi0);
    float m1 = 0.5f * (lo1 + hi1);
    float m2 = 0.5f * (lo2 + hi2);

    const float4* xp = reinterpret_cast<const float4*>(x + 3 * start);
    float pr[CHUNK];
#pragma unroll
    for (int g = 0; g < CHUNK / 4; ++g) {
        const float4 pa = xp[3*g + 0];
        const float4 pb = xp[3*g + 1];
        const float4 pc = xp[3*g + 2];
        MS(4*g + 0, pa.x, pa.y, pa.z);
        MS(4*g + 1, pa.w, pb.x, pb.y);
        MS(4*g + 2, pb.z, pb.w, pc.x);
        MS(4*g + 3, pc.y, pc.z, pc.w);
    }

    float4* op = reinterpret_cast<float4*>(out + start);
#pragma unroll
    for (int i = 0; i < CHUNK / 4; ++i)
        op[i] = make_float4(pr[4*i + 0], pr[4*i + 1], pr[4*i + 2], pr[4*i + 3]);
}

extern "C" void kernel_launch(void* const* d_in, const int* in_sizes, int n_in,
                              void* d_out, int out_size, void* d_ws, size_t ws_size,
                              hipStream_t stream) {
    const float* x   = (const float*)d_in[0];   // (B,1,3)
    const float* W   = (const float*)d_in[1];   // (3,3)
    const float* bv  = (const float*)d_in[2];   // (3,)
    const float* n0v = (const float*)d_in[3];   // (3,1)
    float*       out = (float*)d_out;           // (B,1)
    Updater_65395172049297_kernel<<<GRID, BLOCK, 0, stream>>>(x, W, bv, n0v, out);
}

// Round 2
// 100.963 us; speedup vs baseline: 1.3610x; 1.3610x over previous
//
#include <hip/hip_runtime.h>

// Updater: B=4194304 sequential scan, 3 independent scalar recurrences
//   net' = sigmoid(10*(net + u - 0.5)), u = W*x + b, pred = x . net'
// Chunked-scan parallelization with certified warm-up:
//   map is monotone in net -> trajectories from 0 and 1 bracket the truth.
//   Dual-trajectory warm-up with wave-uniform early exit (-> single traj),
//   geometric global-memory backoff (rare) terminating at exact net0.
// Block stages its whole x window (4096 steps + 32 warm) in LDS once.

#if __has_builtin(__builtin_amdgcn_exp2f)
#define EXP2F(v) __builtin_amdgcn_exp2f(v)
#else
#define EXP2F(v) __expf(0.6931471805599453f * (v))
#endif

namespace {
constexpr int   BTOT   = 4194304;
constexpr int   CHUNK  = 16;                  // output steps per thread
constexpr int   BLOCK  = 256;
constexpr int   BSTEPS = BLOCK * CHUNK;       // 4096 steps per block
constexpr int   WARM   = 32;                  // LDS warm-up window
constexpr int   GRID   = BTOT / BSTEPS;       // 1024 blocks
constexpr int   LDSF   = (BSTEPS + WARM) * 3; // 12384 floats = 49.5 KB
constexpr float KEXP   = -14.426950408889634f; // -10 * log2(e)
constexpr float EPS    = 1e-6f;
}

// sigmoid(10*(n+u-0.5)) = rcp(1 + exp2(KEXP*n + c)), c = (KEXP*W)x + KEXP*(b-.5)
#define CVALS(X0, X1, X2)                                                     \
  const float c0 = fmaf(kw00, (X0), fmaf(kw01, (X1), fmaf(kw02, (X2), kb0)));  \
  const float c1 = fmaf(kw10, (X0), fmaf(kw11, (X1), fmaf(kw12, (X2), kb1)));  \
  const float c2 = fmaf(kw20, (X0), fmaf(kw21, (X1), fmaf(kw22, (X2), kb2)));

#define SIG(N, C) __builtin_amdgcn_rcpf(1.0f + EXP2F(fmaf(KEXP, (N), (C))))

// dual-trajectory (bracket) step
#define US(X0, X1, X2)                                                        \
  do {                                                                        \
    CVALS(X0, X1, X2)                                                         \
    lo0 = SIG(lo0, c0); hi0 = SIG(hi0, c0);                                   \
    lo1 = SIG(lo1, c1); hi1 = SIG(hi1, c1);                                   \
    lo2 = SIG(lo2, c2); hi2 = SIG(hi2, c2);                                   \
  } while (0)

// single-trajectory step (no pred)
#define SS(X0, X1, X2)                                                        \
  do {                                                                        \
    CVALS(X0, X1, X2)                                                         \
    m0 = SIG(m0, c0); m1 = SIG(m1, c1); m2 = SIG(m2, c2);                     \
  } while (0)

// main step: advance + pred
#define MS(IDX, X0, X1, X2)                                                   \
  do {                                                                        \
    CVALS(X0, X1, X2)                                                         \
    m0 = SIG(m0, c0); m1 = SIG(m1, c1); m2 = SIG(m2, c2);                     \
    pr[(IDX)] = fmaf((X0), m0, fmaf((X1), m1, (X2) * m2));                    \
  } while (0)

__global__ __launch_bounds__(BLOCK) void Updater_65395172049297_kernel(
    const float* __restrict__ x, const float* __restrict__ W,
    const float* __restrict__ bv, const float* __restrict__ n0v,
    float* __restrict__ out)
{
    __shared__ float lds[LDSF];

    const float kw00 = KEXP * W[0], kw01 = KEXP * W[1], kw02 = KEXP * W[2];
    const float kw10 = KEXP * W[3], kw11 = KEXP * W[4], kw12 = KEXP * W[5];
    const float kw20 = KEXP * W[6], kw21 = KEXP * W[7], kw22 = KEXP * W[8];
    const float kb0 = KEXP * (bv[0] - 0.5f);
    const float kb1 = KEXP * (bv[1] - 0.5f);
    const float kb2 = KEXP * (bv[2] - 0.5f);
    const float n00 = n0v[0], n01 = n0v[1], n02 = n0v[2];

    // ---- stage block window (steps S-WARM .. S+BSTEPS) into LDS ----
    const long S = (long)blockIdx.x * BSTEPS;
    if (blockIdx.x == 0) {
        const float4* src = reinterpret_cast<const float4*>(x);
        float4*       dst = reinterpret_cast<float4*>(lds + WARM * 3);
        for (int i = threadIdx.x; i < BSTEPS * 3 / 4; i += BLOCK) dst[i] = src[i];
    } else {
        const float4* src = reinterpret_cast<const float4*>(x + 3 * (S - WARM));
        float4*       dst = reinterpret_cast<float4*>(lds);
        for (int i = threadIdx.x; i < LDSF / 4; i += BLOCK) dst[i] = src[i];
    }
    __syncthreads();

    const int  t     = threadIdx.x;
    const long start = S + (long)t * CHUNK;
    const int  wl    = (int)((start < (long)WARM) ? start : (long)WARM);
    const bool exact = (start - wl) == 0;          // warm-up reaches t=0
    const int  gw    = wl >> 2;                    // warm groups of 4 steps
    const int  lbeg  = (int)(start - S + WARM) * 3 - wl * 3; // LDS idx, warm begin

    float lo0, lo1, lo2, hi0, hi1, hi2, m0, m1, m2;
    bool  conv = false;
    int   g    = 0;

    if (exact) {
        m0 = n00; m1 = n01; m2 = n02; conv = true;
    } else {
        lo0 = lo1 = lo2 = 0.0f; hi0 = hi1 = hi2 = 1.0f;
        for (; g < gw; ) {
            const float4* p = reinterpret_cast<const float4*>(&lds[lbeg + 12 * g]);
            const float4 a = p[0], b4 = p[1], c4 = p[2];
            US(a.x, a.y, a.z);
            US(a.w, b4.x, b4.y);
            US(b4.z, b4.w, c4.x);
            US(c4.y, c4.z, c4.w);
            ++g;
            conv = ((hi0 - lo0) < EPS) & ((hi1 - lo1) < EPS) & ((hi2 - lo2) < EPS);
            if (__all(conv)) break;
        }
        if (conv) { m0 = 0.5f * (lo0 + hi0); m1 = 0.5f * (lo1 + hi1); m2 = 0.5f * (lo2 + hi2); }
    }

    if (conv) {
        // single-trajectory remainder of warm-up (from LDS)
        for (; g < gw; ++g) {
            const float4* p = reinterpret_cast<const float4*>(&lds[lbeg + 12 * g]);
            const float4 a = p[0], b4 = p[1], c4 = p[2];
            SS(a.x, a.y, a.z);
            SS(a.w, b4.x, b4.y);
            SS(b4.z, b4.w, c4.x);
            SS(c4.y, c4.z, c4.w);
        }
    } else {
        // rare certified backoff: extend warm-up 4x each attempt (global reads)
        for (int a = 1; a < 10 && !conv; ++a) {
            long wl2 = (long)WARM << (2 * a);
            long bgn = start - wl2;
            bool ex2 = (bgn <= 0);
            if (ex2) bgn = 0;
            if (ex2) { lo0 = hi0 = n00; lo1 = hi1 = n01; lo2 = hi2 = n02; }
            else     { lo0 = lo1 = lo2 = 0.0f; hi0 = hi1 = hi2 = 1.0f; }
            for (long s2 = bgn; s2 < start; ++s2) {
                const float X0 = x[3 * s2], X1 = x[3 * s2 + 1], X2 = x[3 * s2 + 2];
                US(X0, X1, X2);
            }
            conv = ex2 || (((hi0 - lo0) < EPS) & ((hi1 - lo1) < EPS) & ((hi2 - lo2) < EPS));
        }
        m0 = 0.5f * (lo0 + hi0); m1 = 0.5f * (lo1 + hi1); m2 = 0.5f * (lo2 + hi2);
    }

    // ---- main chunk: 16 steps from LDS, preds to registers ----
    const int lm = (int)(start - S + WARM) * 3;   // = 48*t + 96
    float pr[CHUNK];
#pragma unroll
    for (int q = 0; q < CHUNK / 4; ++q) {
        const float4* p = reinterpret_cast<const float4*>(&lds[lm + 12 * q]);
        const float4 a = p[0], b4 = p[1], c4 = p[2];
        MS(4 * q + 0, a.x, a.y, a.z);
        MS(4 * q + 1, a.w, b4.x, b4.y);
        MS(4 * q + 2, b4.z, b4.w, c4.x);
        MS(4 * q + 3, c4.y, c4.z, c4.w);
    }

    float4* op = reinterpret_cast<float4*>(out + start);
#pragma unroll
    for (int i = 0; i < CHUNK / 4; ++i)
        op[i] = make_float4(pr[4 * i + 0], pr[4 * i + 1], pr[4 * i + 2], pr[4 * i + 3]);
}

extern "C" void kernel_launch(void* const* d_in, const int* in_sizes, int n_in,
                              void* d_out, int out_size, void* d_ws, size_t ws_size,
                              hipStream_t stream) {
    const float* x   = (const float*)d_in[0];   // (B,1,3)
    const float* W   = (const float*)d_in[1];   // (3,3)
    const float* bv  = (const float*)d_in[2];   // (3,)
    const float* n0v = (const float*)d_in[3];   // (3,1)
    float*       out = (float*)d_out;           // (B,1)
    Updater_65395172049297_kernel<<<GRID, BLOCK, 0, stream>>>(x, W, bv, n0v, out);
}